// Round 4
// baseline (20705.862 us; speedup 1.0000x reference)
//
#include <hip/hip_runtime.h>
#include <hip/hip_bf16.h>
#include <math.h>

// NERBertWithCRF — round 4.
// RESOLVED dtypes: ALL float tensors are float32 (per reference setup_inputs);
// ints are int32; output is float32 (out[0]=llh, out[1..]=decoded tags).
// The "(bf16)" in the test label = bf16-grade tolerance (2% rel), not storage.

#define Bz 32
#define Lz 128
#define DMz 768
#define NLz 12
#define NHz 12
#define DHz 64
#define FFz 3072
#define Kz 9
#define Tz 127
#define RR (Bz * Lz) // 4096 rows

__device__ __forceinline__ float wred(float v) {
#pragma unroll
    for (int o = 32; o > 0; o >>= 1) v += __shfl_down(v, o, 64);
    return v;
}

__global__ void sentinel_k(float* out) {
    if (threadIdx.x == 0) out[0] = 123456.0f;
}

// ---------------- embedding + LayerNorm ----------------
__global__ __launch_bounds__(256) void embed_ln_k(
    const int* __restrict__ ids, const int* __restrict__ tts,
    const float* __restrict__ we, const float* __restrict__ pe, const float* __restrict__ te,
    const float* __restrict__ g, const float* __restrict__ bb, float* __restrict__ X)
{
    int r = blockIdx.x;
    int pos = r & (Lz - 1);
    int tid = threadIdx.x;
    int id = ids[r], tt = tts[r];
    __shared__ float buf[DMz];
    __shared__ float sa[4], sb[4];
    float s = 0.f, s2 = 0.f;
    for (int d = tid; d < DMz; d += 256) {
        float v = we[(size_t)id * DMz + d] + pe[pos * DMz + d] + te[tt * DMz + d];
        buf[d] = v; s += v; s2 += v * v;
    }
    float w1 = wred(s), w2 = wred(s2);
    if ((tid & 63) == 0) { sa[tid >> 6] = w1; sb[tid >> 6] = w2; }
    __syncthreads();
    float S = sa[0] + sa[1] + sa[2] + sa[3];
    float S2 = sb[0] + sb[1] + sb[2] + sb[3];
    float mean = S * (1.f / DMz);
    float var = S2 * (1.f / DMz) - mean * mean;
    float inv = rsqrtf(var + 1e-12f);
    for (int d = tid; d < DMz; d += 256)
        X[(size_t)r * DMz + d] = (buf[d] - mean) * inv * g[d] + bb[d];
}

// ---------------- residual add + LayerNorm (in-place into X) ----------------
__global__ __launch_bounds__(256) void addln_k(
    float* __restrict__ X, const float* __restrict__ Y,
    const float* __restrict__ g, const float* __restrict__ bb)
{
    int r = blockIdx.x;
    int tid = threadIdx.x;
    __shared__ float buf[DMz];
    __shared__ float sa[4], sb2[4];
    size_t base = (size_t)r * DMz;
    float s = 0.f, s2 = 0.f;
    for (int d = tid; d < DMz; d += 256) {
        float v = X[base + d] + Y[base + d];
        buf[d] = v; s += v; s2 += v * v;
    }
    float w1 = wred(s), w2 = wred(s2);
    if ((tid & 63) == 0) { sa[tid >> 6] = w1; sb2[tid >> 6] = w2; }
    __syncthreads();
    float S = sa[0] + sa[1] + sa[2] + sa[3];
    float S2 = sb2[0] + sb2[1] + sb2[2] + sb2[3];
    float mean = S * (1.f / DMz);
    float var = S2 * (1.f / DMz) - mean * mean;
    float inv = rsqrtf(var + 1e-12f);
    for (int d = tid; d < DMz; d += 256)
        X[base + d] = (buf[d] - mean) * inv * g[d] + bb[d];
}

// ---------------- tiled f32 GEMM: C = [accum +] act(A @ W + bias) ----------------
__global__ __launch_bounds__(256) void gemm_k(
    const float* __restrict__ A, int lda, const float* __restrict__ W, int ldw,
    const float* __restrict__ bias, float* __restrict__ C, int ldc,
    int Kd, int act, int accum)
{
    __shared__ __align__(16) float As[16][68];
    __shared__ __align__(16) float Ws[16][68];
    int tid = threadIdx.x;
    int tx = tid & 15, ty = tid >> 4;
    int row0 = blockIdx.y * 64, col0 = blockIdx.x * 64;
    float acc[4][4] = {};
    for (int k0 = 0; k0 < Kd; k0 += 16) {
        for (int i = tid; i < 1024; i += 256) {
            int kk = i & 15, m = i >> 4;
            As[kk][m] = A[(size_t)(row0 + m) * lda + k0 + kk];
        }
        for (int i = tid; i < 1024; i += 256) {
            int cc = i & 63, kk = i >> 6;
            Ws[kk][cc] = W[(size_t)(k0 + kk) * ldw + col0 + cc];
        }
        __syncthreads();
#pragma unroll
        for (int kk = 0; kk < 16; kk++) {
            float4 a4 = *(const float4*)&As[kk][ty * 4];
            float4 b4 = *(const float4*)&Ws[kk][tx * 4];
            float av[4] = { a4.x, a4.y, a4.z, a4.w };
            float bv[4] = { b4.x, b4.y, b4.z, b4.w };
#pragma unroll
            for (int i = 0; i < 4; i++)
#pragma unroll
                for (int j = 0; j < 4; j++)
                    acc[i][j] = fmaf(av[i], bv[j], acc[i][j]);
        }
        __syncthreads();
    }
#pragma unroll
    for (int i = 0; i < 4; i++) {
        size_t rbase = (size_t)(row0 + ty * 4 + i) * ldc + col0 + tx * 4;
        float4 o;
        float* op = (float*)&o;
#pragma unroll
        for (int j = 0; j < 4; j++) {
            float v = acc[i][j];
            if (bias) v += bias[col0 + tx * 4 + j];
            if (act == 1) v = 0.5f * v * (1.0f + erff(v * 0.70710678118f));
            if (accum) v += C[rbase + j];
            op[j] = v;
        }
        *(float4*)&C[rbase] = o;
    }
}

// ---------------- attention: flash-style, one block per (b,h), 128 threads = q rows ----------------
__global__ __launch_bounds__(128) void attn_k(
    const float* __restrict__ Q, const float* __restrict__ Kb, const float* __restrict__ Vb,
    const int* __restrict__ am, float* __restrict__ CTX)
{
    int bh = blockIdx.x;
    int b = bh / NHz, h = bh - b * NHz;
    __shared__ float Ks[64][DHz];
    __shared__ float Vs[64][DHz];
    int tid = threadIdx.x;
    float qreg[DHz];
    {
        const float* qp = Q + (size_t)(b * Lz + tid) * DMz + h * DHz;
#pragma unroll
        for (int d = 0; d < DHz; d++) qreg[d] = qp[d];
    }
    float m = -INFINITY, l = 0.f;
    float ctx[DHz];
#pragma unroll
    for (int d = 0; d < DHz; d++) ctx[d] = 0.f;
    for (int kc = 0; kc < Lz; kc += 64) {
        __syncthreads();
        for (int i = tid; i < 64 * DHz; i += 128) {
            int kk = i >> 6, d = i & 63;
            size_t base = (size_t)(b * Lz + kc + kk) * DMz + h * DHz + d;
            Ks[kk][d] = Kb[base];
            Vs[kk][d] = Vb[base];
        }
        __syncthreads();
        for (int k = 0; k < 64; k++) {
            float s = 0.f;
#pragma unroll
            for (int d = 0; d < DHz; d++) s = fmaf(qreg[d], Ks[k][d], s);
            s = s * 0.125f + (1.0f - (float)am[b * Lz + kc + k]) * -1e9f;
            float nm = fmaxf(m, s);
            float alpha = __expf(m - nm);
            float p = __expf(s - nm);
            l = l * alpha + p;
#pragma unroll
            for (int d = 0; d < DHz; d++) ctx[d] = ctx[d] * alpha + p * Vs[k][d];
            m = nm;
        }
    }
    float inv = 1.0f / l;
    float* cp = CTX + (size_t)(b * Lz + tid) * DMz + h * DHz;
#pragma unroll
    for (int d = 0; d < DHz; d++) cp[d] = ctx[d] * inv;
}

// ---------------- head: em[b,t,:] = x[b,t+1,:] @ head_W + head_b ----------------
__global__ __launch_bounds__(64) void head_k(
    const float* __restrict__ X, const float* __restrict__ hW, const float* __restrict__ hb,
    float* __restrict__ EM)
{
    int rt = blockIdx.x;
    int b = rt / Tz, t = rt - b * Tz;
    int lane = threadIdx.x;
    const float* xp = X + (size_t)(b * Lz + t + 1) * DMz;
    float acc[Kz];
#pragma unroll
    for (int k = 0; k < Kz; k++) acc[k] = 0.f;
    for (int d = lane; d < DMz; d += 64) {
        float xv = xp[d];
#pragma unroll
        for (int k = 0; k < Kz; k++) acc[k] = fmaf(xv, hW[d * Kz + k], acc[k]);
    }
#pragma unroll
    for (int k = 0; k < Kz; k++) acc[k] = wred(acc[k]);
    if (lane == 0) {
#pragma unroll
        for (int k = 0; k < Kz; k++) EM[(size_t)rt * Kz + k] = acc[k] + hb[k];
    }
}

// ---------------- CRF: lanes 0..31 = forward/llh, lanes 64..95 = viterbi. f32 out ----------------
__global__ __launch_bounds__(128) void crf_k(
    const float* __restrict__ EM, const int* __restrict__ yt, const int* __restrict__ am,
    const float* __restrict__ cs, const float* __restrict__ ce, const float* __restrict__ ctr,
    int* __restrict__ hist, float* __restrict__ out)
{
    __shared__ float tr[Kz * Kz], st[Kz], en[Kz], nums[Bz], Zs[Bz];
    int tid = threadIdx.x;
    if (tid < Kz * Kz) tr[tid] = ctr[tid];
    if (tid < Kz) { st[tid] = cs[tid]; en[tid] = ce[tid]; }
    __syncthreads();
    if (tid < Bz) {
        int b = tid;
        const float* em = EM + (size_t)b * Tz * Kz;
        const int* y = yt + b * Tz;
        const int* mr = am + b * Lz; // mask_tm[t] == mr[t+1]
        float num = st[y[0]] + em[y[0]];
        for (int t = 1; t < Tz; t++) {
            float mf = (mr[t + 1] != 0) ? 1.f : 0.f;
            num += (tr[y[t - 1] * Kz + y[t]] + em[t * Kz + y[t]]) * mf;
        }
        int lastidx = -1;
        for (int t = 0; t < Tz; t++) lastidx += (mr[t + 1] != 0) ? 1 : 0;
        num += en[y[lastidx]];
        nums[b] = num;
        float alpha[Kz];
#pragma unroll
        for (int j = 0; j < Kz; j++) alpha[j] = st[j] + em[j];
        for (int t = 1; t < Tz; t++) {
            bool mm = mr[t + 1] != 0;
            float nxt[Kz];
            for (int j = 0; j < Kz; j++) {
                float mx = -1e30f;
                for (int i = 0; i < Kz; i++) mx = fmaxf(mx, alpha[i] + tr[i * Kz + j]);
                float sm = 0.f;
                for (int i = 0; i < Kz; i++) sm += expf(alpha[i] + tr[i * Kz + j] - mx);
                nxt[j] = mx + logf(sm) + em[t * Kz + j];
            }
            if (mm) { for (int j = 0; j < Kz; j++) alpha[j] = nxt[j]; }
        }
        float mx = -1e30f;
        for (int j = 0; j < Kz; j++) mx = fmaxf(mx, alpha[j] + en[j]);
        float sm = 0.f;
        for (int j = 0; j < Kz; j++) sm += expf(alpha[j] + en[j] - mx);
        Zs[b] = mx + logf(sm);
    } else if (tid >= 64 && tid < 64 + Bz) {
        int b = tid - 64;
        const float* em = EM + (size_t)b * Tz * Kz;
        const int* mr = am + b * Lz;
        int* hb = hist + (size_t)b * (Tz - 1) * Kz;
        float sc[Kz];
#pragma unroll
        for (int j = 0; j < Kz; j++) sc[j] = st[j] + em[j];
        for (int t = 1; t < Tz; t++) {
            bool mm = mr[t + 1] != 0;
            float nxt[Kz]; int arg[Kz];
            for (int j = 0; j < Kz; j++) {
                float best = -1e30f; int bi = 0;
                for (int i = 0; i < Kz; i++) {
                    float v = sc[i] + tr[i * Kz + j];
                    if (v > best) { best = v; bi = i; }
                }
                nxt[j] = best + em[t * Kz + j]; arg[j] = bi;
            }
            for (int j = 0; j < Kz; j++) hb[(size_t)(t - 1) * Kz + j] = arg[j];
            if (mm) { for (int j = 0; j < Kz; j++) sc[j] = nxt[j]; }
        }
        float best = -1e30f; int last = 0;
        for (int j = 0; j < Kz; j++) { float v = sc[j] + en[j]; if (v > best) { best = v; last = j; } }
        int tag = last;
        for (int t = Tz - 2; t >= 0; t--) {
            out[1 + b * Tz + (t + 1)] = (float)tag;
            int prev = hb[(size_t)t * Kz + tag];
            if (mr[t + 2] != 0) tag = prev;
        }
        out[1 + b * Tz] = (float)tag;
    }
    __syncthreads();
    if (tid == 0) {
        float s = 0.f;
        for (int b = 0; b < Bz; b++) s += nums[b] - Zs[b];
        out[0] = s * (1.0f / Bz);
    }
}

extern "C" void kernel_launch(void* const* d_in, const int* in_sizes, int n_in,
                              void* d_out, int out_size, void* d_ws, size_t ws_size,
                              hipStream_t stream)
{
    (void)in_sizes; (void)n_in; (void)out_size; (void)ws_size;
    const int* ids    = (const int*)d_in[0];
    const int* amask  = (const int*)d_in[1];
    const int* tts    = (const int*)d_in[2];
    const int* ytrue  = (const int*)d_in[3];
    const float* we   = (const float*)d_in[4];
    const float* pe   = (const float*)d_in[5];
    const float* te   = (const float*)d_in[6];
    const float* eg   = (const float*)d_in[7];
    const float* eb   = (const float*)d_in[8];
    const float* Wq   = (const float*)d_in[9];
    const float* bq   = (const float*)d_in[10];
    const float* Wk   = (const float*)d_in[11];
    const float* bk   = (const float*)d_in[12];
    const float* Wv   = (const float*)d_in[13];
    const float* bv   = (const float*)d_in[14];
    const float* Wo   = (const float*)d_in[15];
    const float* bo   = (const float*)d_in[16];
    const float* ln1g = (const float*)d_in[17];
    const float* ln1b = (const float*)d_in[18];
    const float* W1   = (const float*)d_in[19];
    const float* b1   = (const float*)d_in[20];
    const float* W2   = (const float*)d_in[21];
    const float* b2   = (const float*)d_in[22];
    const float* ln2g = (const float*)d_in[23];
    const float* ln2b = (const float*)d_in[24];
    const float* hW   = (const float*)d_in[25];
    const float* hb   = (const float*)d_in[26];
    const float* cs   = (const float*)d_in[27];
    const float* ce   = (const float*)d_in[28];
    const float* ctr  = (const float*)d_in[29];

    float* ws = (float*)d_ws;
    size_t RDM = (size_t)RR * DMz;
    float* X  = ws;
    float* B1 = X  + RDM;
    float* B2 = B1 + RDM;
    float* B3 = B2 + RDM;
    float* B4 = B3 + RDM;
    float* F  = B2;                    // 4096x1536 aliases B2+B3 exactly
    float* EM = B4 + RDM;
    int* HIST = (int*)(EM + Bz * Tz * Kz);
    // total ws: 5*RDM*4 + ~0.3MB ≈ 60.3 MB

    (void)hipGetLastError();
    sentinel_k<<<1, 64, 0, stream>>>((float*)d_out);
    embed_ln_k<<<RR, 256, 0, stream>>>(ids, tts, we, pe, te, eg, eb, X);
    for (int l = 0; l < NLz; l++) {
        size_t wofs = (size_t)l * DMz * DMz;
        gemm_k<<<dim3(12, 64), 256, 0, stream>>>(X, DMz, Wq + wofs, DMz, bq + l * DMz, B1, DMz, DMz, 0, 0);
        gemm_k<<<dim3(12, 64), 256, 0, stream>>>(X, DMz, Wk + wofs, DMz, bk + l * DMz, B2, DMz, DMz, 0, 0);
        gemm_k<<<dim3(12, 64), 256, 0, stream>>>(X, DMz, Wv + wofs, DMz, bv + l * DMz, B3, DMz, DMz, 0, 0);
        attn_k<<<Bz * NHz, 128, 0, stream>>>(B1, B2, B3, amask, B4);
        gemm_k<<<dim3(12, 64), 256, 0, stream>>>(B4, DMz, Wo + wofs, DMz, bo + l * DMz, B1, DMz, DMz, 0, 0);
        addln_k<<<RR, 256, 0, stream>>>(X, B1, ln1g + l * DMz, ln1b + l * DMz);
        const float* W1l = W1 + (size_t)l * DMz * FFz;
        const float* W2l = W2 + (size_t)l * FFz * DMz;
        gemm_k<<<dim3(24, 64), 256, 0, stream>>>(X, DMz, W1l, FFz, b1 + (size_t)l * FFz, F, 1536, DMz, 1, 0);
        gemm_k<<<dim3(12, 64), 256, 0, stream>>>(F, 1536, W2l, DMz, b2 + l * DMz, B1, DMz, 1536, 0, 0);
        gemm_k<<<dim3(24, 64), 256, 0, stream>>>(X, DMz, W1l + 1536, FFz, b1 + (size_t)l * FFz + 1536, F, 1536, DMz, 1, 0);
        gemm_k<<<dim3(12, 64), 256, 0, stream>>>(F, 1536, W2l + (size_t)1536 * DMz, DMz, nullptr, B1, DMz, 1536, 0, 1);
        addln_k<<<RR, 256, 0, stream>>>(X, B1, ln2g + l * DMz, ln2b + l * DMz);
    }
    head_k<<<Bz * Tz, 64, 0, stream>>>(X, hW, hb, EM);
    crf_k<<<1, 128, 0, stream>>>(EM, ytrue, amask, cs, ce, ctr, HIST, (float*)d_out);

    if (hipGetLastError() != hipSuccess) {
        hipMemsetAsync(d_out, 0xFF, 4, stream); // out[0] -> f32 NaN signal
    }
}